// Round 2
// baseline (59.556 us; speedup 1.0000x reference)
//
#include <hip/hip_runtime.h>
#include <hip/hip_bf16.h>

// Problem: B=4096, D_IN=D_H=K=1024.
//   x = input_ @ fq(Wi,4).T + bi ; h = hidden @ fq(Wr,4).T + br
//   out = tanh(LN(x) + LN(h))
// ws layout: [0,8)        : 2x uint absmax bits (atomicMax)
//            +256         : Qi  bf16 ints, 2 MB
//            +256+2M      : Qr  bf16 ints, 2 MB
//            +256+4M      : Abf bf16, 8 MB
//            +256+12M     : Hbf bf16, 8 MB
//            +256+20M     : Hbuf f32, 16 MB   (x goes to d_out)

typedef float  f32x4  __attribute__((ext_vector_type(4)));
typedef __bf16 bf16x8 __attribute__((ext_vector_type(8)));

#define KDIM 1024

// ---------------- absmax over each weight tensor ----------------
__global__ __launch_bounds__(256)
void absmax_k(const float* __restrict__ Wi, const float* __restrict__ Wr,
              unsigned* __restrict__ hdr)
{
    const float* W = blockIdx.y ? Wr : Wi;
    const int t = threadIdx.x;
    const int lane = t & 63, wid = t >> 6;
    const f32x4* p = (const f32x4*)W;
    const size_t base = (size_t)blockIdx.x * 1024;   // 1024 float4 per block
    float m = 0.f;
#pragma unroll
    for (int k = 0; k < 4; ++k) {
        f32x4 v = p[base + k * 256 + t];
        m = fmaxf(m, fmaxf(fmaxf(fabsf(v[0]), fabsf(v[1])),
                           fmaxf(fabsf(v[2]), fabsf(v[3]))));
    }
#pragma unroll
    for (int o = 32; o >= 1; o >>= 1) m = fmaxf(m, __shfl_xor(m, o));
    __shared__ float wm_[4];
    if (lane == 0) wm_[wid] = m;
    __syncthreads();
    if (t == 0) {
        m = fmaxf(fmaxf(wm_[0], wm_[1]), fmaxf(wm_[2], wm_[3]));
        atomicMax(hdr + blockIdx.y, __float_as_uint(m));
    }
}

// ---------------- prep: quantize weights + convert activations to bf16 ----------------
// blocks 0..1023: input_ -> Abf   1024..2047: hidden -> Hbf
// blocks 2048..2303: Wi -> Qi (int bf16)   2304..2559: Wr -> Qr
__global__ __launch_bounds__(256)
void prep_k(const float* __restrict__ A, const float* __restrict__ Hh,
            const float* __restrict__ Wi, const float* __restrict__ Wr,
            const float* __restrict__ hdrf,
            __bf16* __restrict__ Abf, __bf16* __restrict__ Hbf,
            __bf16* __restrict__ Qi, __bf16* __restrict__ Qr)
{
    const int b = blockIdx.x, t = threadIdx.x;
    const float* src; __bf16* dst; int base; bool doq = false; float s = 1.f;
    if (b < 1024)      { src = A;  dst = Abf; base = b * 4096; }
    else if (b < 2048) { src = Hh; dst = Hbf; base = (b - 1024) * 4096; }
    else if (b < 2304) { src = Wi; dst = Qi;  base = (b - 2048) * 4096; doq = true; s = hdrf[0] / 7.0f; }
    else               { src = Wr; dst = Qr;  base = (b - 2304) * 4096; doq = true; s = hdrf[1] / 7.0f; }
#pragma unroll
    for (int j = 0; j < 2; ++j) {
        const int e = base + (j * 256 + t) * 8;
        f32x4 v0 = ((const f32x4*)(src + e))[0];
        f32x4 v1 = ((const f32x4*)(src + e))[1];
        bf16x8 o;
        if (doq) {
#pragma unroll
            for (int i = 0; i < 4; ++i) {
                o[i]     = (__bf16)rintf(v0[i] / s);
                o[i + 4] = (__bf16)rintf(v1[i] / s);
            }
        } else {
#pragma unroll
            for (int i = 0; i < 4; ++i) {
                o[i]     = (__bf16)v0[i];
                o[i + 4] = (__bf16)v1[i];
            }
        }
        *(bf16x8*)(dst + e) = o;
    }
}

// ---------------- dual bf16 MFMA GEMM (m97 structure) ----------------
// 128x128 tile, BK=64, 4 waves of 64x64, 16x16x32 MFMA.
// LDS linear chunks (global_load_lds), swizzle applied on the per-lane GLOBAL
// source address: LDS chunk (row, g') holds global k-group g = g' ^ (row&7).
// ds_read then uses slot row*8 + (g ^ (row&7)) -> conflict-free b128 reads.
__global__ __launch_bounds__(256, 2)
void gemm_dual(const __bf16* __restrict__ A0, const __bf16* __restrict__ A1,
               const __bf16* __restrict__ W0, const __bf16* __restrict__ W1,
               float* __restrict__ C0, float* __restrict__ C1)
{
    __shared__ bf16x8 lds[2][2][1024];   // [buf][A/B][chunk] = 64 KB

    // XCD-aware bijective swizzle (512 blocks, 8 XCDs)
    const int b = blockIdx.x;
    const int swz = (b & 7) * 64 + (b >> 3);
    const int which = swz >> 8;
    const int r = swz & 255;
    const int bm = r >> 3, bn = r & 7;

    const __bf16* A = which ? A1 : A0;
    const __bf16* W = which ? W1 : W0;
    float*        C = which ? C1 : C0;

    const int t = threadIdx.x;
    const int l = t & 63, w = t >> 6;
    const int wm = w >> 1, wn = w & 1;

    const __bf16* gA = A + (size_t)(bm * 128) * KDIM;
    const __bf16* gB = W + (size_t)(bn * 128) * KDIM;

    // per-lane staging source offsets (element units), swizzled
    int srcOffA[4], srcOffB[4];
#pragma unroll
    for (int j = 0; j < 4; ++j) {
        const int c = (w * 4 + j) * 64 + l;
        const int row = c >> 3;
        const int g = (c & 7) ^ (row & 7);
        srcOffA[j] = row * KDIM + g * 8;
        srcOffB[j] = row * KDIM + g * 8;
    }

    const f32x4 zero4 = {0.f, 0.f, 0.f, 0.f};
    f32x4 acc[4][4];
#pragma unroll
    for (int mi = 0; mi < 4; ++mi)
#pragma unroll
        for (int ni = 0; ni < 4; ++ni) acc[mi][ni] = zero4;

#define STAGE(bb, kt)                                                          \
    do {                                                                       \
        _Pragma("unroll")                                                      \
        for (int j = 0; j < 4; ++j) {                                          \
            __builtin_amdgcn_global_load_lds(                                  \
                (const __attribute__((address_space(1))) unsigned*)            \
                    (gA + srcOffA[j] + (kt) * 64),                             \
                (__attribute__((address_space(3))) unsigned*)                  \
                    (&lds[bb][0][(w * 4 + j) * 64]),                           \
                16, 0, 0);                                                     \
            __builtin_amdgcn_global_load_lds(                                  \
                (const __attribute__((address_space(1))) unsigned*)            \
                    (gB + srcOffB[j] + (kt) * 64),                             \
                (__attribute__((address_space(3))) unsigned*)                  \
                    (&lds[bb][1][(w * 4 + j) * 64]),                           \
                16, 0, 0);                                                     \
        }                                                                      \
    } while (0)

    STAGE(0, 0);

    int cur = 0;
    for (int kt = 0; kt < 16; ++kt) {
        __syncthreads();                   // buf[cur] staged, prior reads done
        if (kt < 15) STAGE(cur ^ 1, kt + 1);

        const bf16x8* ldsA = &lds[cur][0][0];
        const bf16x8* ldsB = &lds[cur][1][0];
#pragma unroll
        for (int kk = 0; kk < 2; ++kk) {
            bf16x8 af[4], bfv[4];
            const int kq = kk * 4 + (l >> 4);
            const int x7 = l & 7;
#pragma unroll
            for (int mi = 0; mi < 4; ++mi) {
                const int row = wm * 64 + mi * 16 + (l & 15);
                af[mi] = ldsA[row * 8 + (kq ^ x7)];
            }
#pragma unroll
            for (int ni = 0; ni < 4; ++ni) {
                const int row = wn * 64 + ni * 16 + (l & 15);
                bfv[ni] = ldsB[row * 8 + (kq ^ x7)];
            }
#pragma unroll
            for (int mi = 0; mi < 4; ++mi)
#pragma unroll
                for (int ni = 0; ni < 4; ++ni)
                    acc[mi][ni] = __builtin_amdgcn_mfma_f32_16x16x32_bf16(
                        af[mi], bfv[ni], acc[mi][ni], 0, 0, 0);
        }
        cur ^= 1;
    }

    // C write: row = (lane>>4)*4 + reg, col = lane&15  (m89-verified layout)
    const int rbase = bm * 128 + wm * 64 + ((l >> 4) << 2);
    const int cbase = bn * 128 + wn * 64 + (l & 15);
#pragma unroll
    for (int mi = 0; mi < 4; ++mi)
#pragma unroll
        for (int ni = 0; ni < 4; ++ni)
#pragma unroll
            for (int rr = 0; rr < 4; ++rr)
                C[(size_t)(rbase + mi * 16 + rr) * KDIM + cbase + ni * 16] =
                    acc[mi][ni][rr];
#undef STAGE
}

// ---------------- fused scale+bias, LN(x), LN(h), tanh ----------------
__global__ __launch_bounds__(256)
void ln_tanh_k(const float* __restrict__ X, const float* __restrict__ Hh,
               const float* __restrict__ bi, const float* __restrict__ br,
               const float* __restrict__ hdrf, float* __restrict__ out)
{
    const int row = blockIdx.x;
    const int t = threadIdx.x;
    const int lane = t & 63, wid = t >> 6;
    const float si = hdrf[0] / 7.0f;
    const float sr = hdrf[1] / 7.0f;

    f32x4 xv = ((const f32x4*)(X  + (size_t)row * 1024))[t];
    f32x4 hv = ((const f32x4*)(Hh + (size_t)row * 1024))[t];
    f32x4 bvi = ((const f32x4*)bi)[t];
    f32x4 bvr = ((const f32x4*)br)[t];

    float xs[4], hs[4];
    float sx = 0.f, sh = 0.f;
#pragma unroll
    for (int j = 0; j < 4; ++j) {
        xs[j] = xv[j] * si + bvi[j];
        hs[j] = hv[j] * sr + bvr[j];
        sx += xs[j]; sh += hs[j];
    }

    __shared__ float rb[2][4];
#pragma unroll
    for (int o = 32; o >= 1; o >>= 1) { sx += __shfl_xor(sx, o); sh += __shfl_xor(sh, o); }
    if (lane == 0) { rb[0][wid] = sx; rb[1][wid] = sh; }
    __syncthreads();
    sx = rb[0][0] + rb[0][1] + rb[0][2] + rb[0][3];
    sh = rb[1][0] + rb[1][1] + rb[1][2] + rb[1][3];
    const float mx = sx * (1.0f / 1024.0f), mh = sh * (1.0f / 1024.0f);

    float vx = 0.f, vh = 0.f;
#pragma unroll
    for (int j = 0; j < 4; ++j) {
        xs[j] -= mx; hs[j] -= mh;
        vx += xs[j] * xs[j]; vh += hs[j] * hs[j];
    }
    __syncthreads();   // rb reuse
#pragma unroll
    for (int o = 32; o >= 1; o >>= 1) { vx += __shfl_xor(vx, o); vh += __shfl_xor(vh, o); }
    if (lane == 0) { rb[0][wid] = vx; rb[1][wid] = vh; }
    __syncthreads();
    vx = rb[0][0] + rb[0][1] + rb[0][2] + rb[0][3];
    vh = rb[1][0] + rb[1][1] + rb[1][2] + rb[1][3];
    const float rsx = rsqrtf(vx * (1.0f / 1024.0f) + 1e-5f);
    const float rsh = rsqrtf(vh * (1.0f / 1024.0f) + 1e-5f);

    f32x4 o4;
#pragma unroll
    for (int j = 0; j < 4; ++j) o4[j] = tanhf(xs[j] * rsx + hs[j] * rsh);
    ((f32x4*)(out + (size_t)row * 1024))[t] = o4;
}

extern "C" void kernel_launch(void* const* d_in, const int* in_sizes, int n_in,
                              void* d_out, int out_size, void* d_ws, size_t ws_size,
                              hipStream_t stream)
{
    const float* input_ = (const float*)d_in[0];
    const float* hidden = (const float*)d_in[1];
    const float* Wi     = (const float*)d_in[2];
    const float* bi     = (const float*)d_in[3];
    const float* Wr     = (const float*)d_in[4];
    const float* br     = (const float*)d_in[5];
    float* out = (float*)d_out;

    char* ws = (char*)d_ws;
    unsigned* hdr  = (unsigned*)ws;
    const float* hdrf = (const float*)ws;
    __bf16* Qi  = (__bf16*)(ws + 256);
    __bf16* Qr  = (__bf16*)(ws + 256 + (1u << 21));
    __bf16* Abf = (__bf16*)(ws + 256 + (2u << 21));
    __bf16* Hbf = (__bf16*)(ws + 256 + (2u << 21) + (1u << 23));
    float*  Hbuf = (float*)(ws + 256 + (2u << 21) + (2u << 23));

    hipMemsetAsync(hdr, 0, 8, stream);
    absmax_k<<<dim3(256, 2), 256, 0, stream>>>(Wi, Wr, hdr);
    prep_k<<<2560, 256, 0, stream>>>(input_, hidden, Wi, Wr, hdrf, Abf, Hbf, Qi, Qr);
    gemm_dual<<<512, 256, 0, stream>>>(Abf, Hbf, Qi, Qr, out, Hbuf);
    ln_tanh_k<<<4096, 256, 0, stream>>>(out, Hbuf, bi, br, hdrf, out);
}

// Round 3
// 56.539 us; speedup vs baseline: 1.0534x; 1.0534x over previous
//
#include <hip/hip_runtime.h>
#include <hip/hip_bf16.h>

// Problem: B=4096, D_IN=D_H=K=1024.
//   x = input_ @ fq(Wi,4).T + bi ; h = hidden @ fq(Wr,4).T + br
//   out = tanh(LN(x) + LN(h))
// ws layout: [0,8)    : 2x uint absmax bits (atomicMax)
//   +256     : Qi  bf16 ints, 2 MB
//   +2M+256  : Qr  bf16 ints, 2 MB
//   +4M+256  : Abf bf16, 8 MB
//   +12M+256 : Hbf bf16, 8 MB
//   +20M+256 : Xq  bf16 (x pre-LN), 8 MB
//   +28M+256 : Hq  bf16 (h pre-LN), 8 MB

typedef float  f32x4  __attribute__((ext_vector_type(4)));
typedef __bf16 bf16x8 __attribute__((ext_vector_type(8)));
typedef __bf16 bf16x4 __attribute__((ext_vector_type(4)));

#define KDIM 1024

// ---------------- fused: absmax (blocks 0..511) + activation cvt (512..2559) ----------------
__global__ __launch_bounds__(256)
void prep1_k(const float* __restrict__ A, const float* __restrict__ Hh,
             const float* __restrict__ Wi, const float* __restrict__ Wr,
             unsigned* __restrict__ hdr,
             __bf16* __restrict__ Abf, __bf16* __restrict__ Hbf)
{
    const int b = blockIdx.x, t = threadIdx.x;
    if (b < 512) {
        // absmax over Wi (b<256) or Wr (b>=256)
        const int tensor = b >> 8;
        const float* W = tensor ? Wr : Wi;
        const int lane = t & 63, wid = t >> 6;
        const f32x4* p = (const f32x4*)W;
        const size_t base = (size_t)(b & 255) * 1024;
        float m = 0.f;
#pragma unroll
        for (int k = 0; k < 4; ++k) {
            f32x4 v = p[base + k * 256 + t];
            m = fmaxf(m, fmaxf(fmaxf(fabsf(v[0]), fabsf(v[1])),
                               fmaxf(fabsf(v[2]), fabsf(v[3]))));
        }
#pragma unroll
        for (int o = 32; o >= 1; o >>= 1) m = fmaxf(m, __shfl_xor(m, o));
        __shared__ float wm_[4];
        if (lane == 0) wm_[wid] = m;
        __syncthreads();
        if (t == 0) {
            m = fmaxf(fmaxf(wm_[0], wm_[1]), fmaxf(wm_[2], wm_[3]));
            atomicMax(hdr + tensor, __float_as_uint(m));
        }
        return;
    }
    // activation f32 -> bf16
    const int c = b - 512;                       // 0..2047
    const float* src = (c < 1024) ? A : Hh;
    __bf16* dst = (c < 1024) ? Abf : Hbf;
    const int base = (c & 1023) * 4096;
#pragma unroll
    for (int j = 0; j < 2; ++j) {
        const int e = base + (j * 256 + t) * 8;
        f32x4 v0 = ((const f32x4*)(src + e))[0];
        f32x4 v1 = ((const f32x4*)(src + e))[1];
        bf16x8 o;
#pragma unroll
        for (int i = 0; i < 4; ++i) {
            o[i]     = (__bf16)v0[i];
            o[i + 4] = (__bf16)v1[i];
        }
        *(bf16x8*)(dst + e) = o;
    }
}

// ---------------- quantize weights to integer bf16 ----------------
__global__ __launch_bounds__(256)
void quant_k(const float* __restrict__ Wi, const float* __restrict__ Wr,
             const float* __restrict__ hdrf,
             __bf16* __restrict__ Qi, __bf16* __restrict__ Qr)
{
    const int tensor = blockIdx.x >> 8;
    const int b = blockIdx.x & 255;
    const float* W = tensor ? Wr : Wi;
    __bf16* Q = tensor ? Qr : Qi;
    const float s = hdrf[tensor] / 7.0f;
    const int t = threadIdx.x;
#pragma unroll
    for (int j = 0; j < 2; ++j) {
        const int e = b * 4096 + (j * 256 + t) * 8;
        f32x4 v0 = ((const f32x4*)(W + e))[0];
        f32x4 v1 = ((const f32x4*)(W + e))[1];
        bf16x8 o;
#pragma unroll
        for (int i = 0; i < 4; ++i) {
            o[i]     = (__bf16)rintf(v0[i] / s);
            o[i + 4] = (__bf16)rintf(v1[i] / s);
        }
        *(bf16x8*)(Q + e) = o;
    }
}

// ---------------- dual bf16 MFMA GEMM (m97 structure, bf16 C) ----------------
// 128x128 tile, BK=64, 4 waves of 64x64, 16x16x32 MFMA.
// LDS linear chunks (global_load_lds), swizzle applied on the per-lane GLOBAL
// source address; ds_read uses slot row*8 + (g ^ (row&7)) -> conflict-free.
// Epilogue: swapped-operand mfma(bfv, af) => lane holds 4 consecutive
// features for one batch row -> single 8B bf16x4 store per fragment.
__global__ __launch_bounds__(256, 2)
void gemm_dual(const __bf16* __restrict__ A0, const __bf16* __restrict__ A1,
               const __bf16* __restrict__ W0, const __bf16* __restrict__ W1,
               __bf16* __restrict__ C0, __bf16* __restrict__ C1)
{
    __shared__ bf16x8 lds[2][2][1024];   // [buf][A/B][chunk] = 64 KB

    // XCD-aware bijective swizzle (512 blocks, 8 XCDs)
    const int b = blockIdx.x;
    const int swz = (b & 7) * 64 + (b >> 3);
    const int which = swz >> 8;
    const int r = swz & 255;
    const int bm = r >> 3, bn = r & 7;

    const __bf16* A = which ? A1 : A0;
    const __bf16* W = which ? W1 : W0;
    __bf16*       C = which ? C1 : C0;

    const int t = threadIdx.x;
    const int l = t & 63, w = t >> 6;
    const int wm = w >> 1, wn = w & 1;

    const __bf16* gA = A + (size_t)(bm * 128) * KDIM;
    const __bf16* gB = W + (size_t)(bn * 128) * KDIM;

    // per-lane staging source offsets (element units), swizzled
    int srcOff[4];
#pragma unroll
    for (int j = 0; j < 4; ++j) {
        const int c = (w * 4 + j) * 64 + l;
        const int row = c >> 3;
        const int g = (c & 7) ^ (row & 7);
        srcOff[j] = row * KDIM + g * 8;
    }

    const f32x4 zero4 = {0.f, 0.f, 0.f, 0.f};
    f32x4 acc[4][4];
#pragma unroll
    for (int mi = 0; mi < 4; ++mi)
#pragma unroll
        for (int ni = 0; ni < 4; ++ni) acc[mi][ni] = zero4;

#define STAGE(bb, kt)                                                          \
    do {                                                                       \
        _Pragma("unroll")                                                      \
        for (int j = 0; j < 4; ++j) {                                          \
            __builtin_amdgcn_global_load_lds(                                  \
                (const __attribute__((address_space(1))) unsigned*)            \
                    (gA + srcOff[j] + (kt) * 64),                              \
                (__attribute__((address_space(3))) unsigned*)                  \
                    (&lds[bb][0][(w * 4 + j) * 64]),                           \
                16, 0, 0);                                                     \
            __builtin_amdgcn_global_load_lds(                                  \
                (const __attribute__((address_space(1))) unsigned*)            \
                    (gB + srcOff[j] + (kt) * 64),                              \
                (__attribute__((address_space(3))) unsigned*)                  \
                    (&lds[bb][1][(w * 4 + j) * 64]),                           \
                16, 0, 0);                                                     \
        }                                                                      \
    } while (0)

    STAGE(0, 0);

    int cur = 0;
    for (int kt = 0; kt < 16; ++kt) {
        __syncthreads();                   // buf[cur] staged, prior reads done
        if (kt < 15) STAGE(cur ^ 1, kt + 1);

        const bf16x8* ldsA = &lds[cur][0][0];
        const bf16x8* ldsB = &lds[cur][1][0];
#pragma unroll
        for (int kk = 0; kk < 2; ++kk) {
            bf16x8 af[4], bfv[4];
            const int kq = kk * 4 + (l >> 4);
            const int x7 = l & 7;
#pragma unroll
            for (int mi = 0; mi < 4; ++mi) {
                const int row = wm * 64 + mi * 16 + (l & 15);
                af[mi] = ldsA[row * 8 + (kq ^ x7)];
            }
#pragma unroll
            for (int ni = 0; ni < 4; ++ni) {
                const int row = wn * 64 + ni * 16 + (l & 15);
                bfv[ni] = ldsB[row * 8 + (kq ^ x7)];
            }
            // swapped operands: D axis (lane>>4)*4+reg = W-rows (features),
            // axis lane&15 = A-rows (batch)
#pragma unroll
            for (int mi = 0; mi < 4; ++mi)
#pragma unroll
                for (int ni = 0; ni < 4; ++ni)
                    acc[mi][ni] = __builtin_amdgcn_mfma_f32_16x16x32_bf16(
                        bfv[ni], af[mi], acc[mi][ni], 0, 0, 0);
        }
        cur ^= 1;
    }

    // C write: batch = lane&15 (+mi*16), feat = (lane>>4)*4 + rr (+ni*16)
    const int batch0 = bm * 128 + wm * 64 + (l & 15);
    const int feat0  = bn * 128 + wn * 64 + ((l >> 4) << 2);
#pragma unroll
    for (int mi = 0; mi < 4; ++mi)
#pragma unroll
        for (int ni = 0; ni < 4; ++ni) {
            bf16x4 o;
#pragma unroll
            for (int rr = 0; rr < 4; ++rr) o[rr] = (__bf16)acc[mi][ni][rr];
            *(bf16x4*)(C + (size_t)(batch0 + mi * 16) * KDIM + feat0 + ni * 16) = o;
        }
#undef STAGE
}

// ---------------- fused scale+bias, LN(x), LN(h), tanh ----------------
__global__ __launch_bounds__(256)
void ln_tanh_k(const __bf16* __restrict__ X, const __bf16* __restrict__ Hh,
               const float* __restrict__ bi, const float* __restrict__ br,
               const float* __restrict__ hdrf, float* __restrict__ out)
{
    const int row = blockIdx.x;
    const int t = threadIdx.x;
    const int lane = t & 63, wid = t >> 6;
    const float si = hdrf[0] / 7.0f;
    const float sr = hdrf[1] / 7.0f;

    bf16x4 xv = ((const bf16x4*)(X  + (size_t)row * 1024))[t];
    bf16x4 hv = ((const bf16x4*)(Hh + (size_t)row * 1024))[t];
    f32x4 bvi = ((const f32x4*)bi)[t];
    f32x4 bvr = ((const f32x4*)br)[t];

    float xs[4], hs[4];
    float sx = 0.f, sh = 0.f;
#pragma unroll
    for (int j = 0; j < 4; ++j) {
        xs[j] = (float)xv[j] * si + bvi[j];
        hs[j] = (float)hv[j] * sr + bvr[j];
        sx += xs[j]; sh += hs[j];
    }

    __shared__ float rb[2][4];
#pragma unroll
    for (int o = 32; o >= 1; o >>= 1) { sx += __shfl_xor(sx, o); sh += __shfl_xor(sh, o); }
    if (lane == 0) { rb[0][wid] = sx; rb[1][wid] = sh; }
    __syncthreads();
    sx = rb[0][0] + rb[0][1] + rb[0][2] + rb[0][3];
    sh = rb[1][0] + rb[1][1] + rb[1][2] + rb[1][3];
    const float mx = sx * (1.0f / 1024.0f), mh = sh * (1.0f / 1024.0f);

    float vx = 0.f, vh = 0.f;
#pragma unroll
    for (int j = 0; j < 4; ++j) {
        xs[j] -= mx; hs[j] -= mh;
        vx += xs[j] * xs[j]; vh += hs[j] * hs[j];
    }
    __syncthreads();   // rb reuse
#pragma unroll
    for (int o = 32; o >= 1; o >>= 1) { vx += __shfl_xor(vx, o); vh += __shfl_xor(vh, o); }
    if (lane == 0) { rb[0][wid] = vx; rb[1][wid] = vh; }
    __syncthreads();
    vx = rb[0][0] + rb[0][1] + rb[0][2] + rb[0][3];
    vh = rb[1][0] + rb[1][1] + rb[1][2] + rb[1][3];
    const float rsx = rsqrtf(vx * (1.0f / 1024.0f) + 1e-5f);
    const float rsh = rsqrtf(vh * (1.0f / 1024.0f) + 1e-5f);

    f32x4 o4;
#pragma unroll
    for (int j = 0; j < 4; ++j) o4[j] = tanhf(xs[j] * rsx + hs[j] * rsh);
    ((f32x4*)(out + (size_t)row * 1024))[t] = o4;
}

extern "C" void kernel_launch(void* const* d_in, const int* in_sizes, int n_in,
                              void* d_out, int out_size, void* d_ws, size_t ws_size,
                              hipStream_t stream)
{
    const float* input_ = (const float*)d_in[0];
    const float* hidden = (const float*)d_in[1];
    const float* Wi     = (const float*)d_in[2];
    const float* bi     = (const float*)d_in[3];
    const float* Wr     = (const float*)d_in[4];
    const float* br     = (const float*)d_in[5];
    float* out = (float*)d_out;

    char* ws = (char*)d_ws;
    unsigned* hdr  = (unsigned*)ws;
    const float* hdrf = (const float*)ws;
    __bf16* Qi  = (__bf16*)(ws + 256);
    __bf16* Qr  = (__bf16*)(ws + 256 + (1u << 21));
    __bf16* Abf = (__bf16*)(ws + 256 + (2u << 21));
    __bf16* Hbf = (__bf16*)(ws + 256 + (2u << 21) + (1u << 23));
    __bf16* Xq  = (__bf16*)(ws + 256 + (2u << 21) + (2u << 23));
    __bf16* Hq  = (__bf16*)(ws + 256 + (2u << 21) + (3u << 23));

    hipMemsetAsync(hdr, 0, 8, stream);
    prep1_k<<<2560, 256, 0, stream>>>(input_, hidden, Wi, Wr, hdr, Abf, Hbf);
    quant_k<<<512, 256, 0, stream>>>(Wi, Wr, hdrf, Qi, Qr);
    gemm_dual<<<512, 256, 0, stream>>>(Abf, Hbf, Qi, Qr, Xq, Hq);
    ln_tanh_k<<<4096, 256, 0, stream>>>(Xq, Hq, bi, br, hdrf, out);
}

// Round 4
// 49.595 us; speedup vs baseline: 1.2009x; 1.1400x over previous
//
#include <hip/hip_runtime.h>
#include <hip/hip_bf16.h>

// Problem: B=4096, D_IN=D_H=K=1024.
//   x = input_ @ fq(Wi,4).T + bi ; h = hidden @ fq(Wr,4).T + br
//   out = tanh(LN(x) + LN(h))
// ws layout:
//   +0      : bmax f32[512] (per-block weight absmax; 0..255 Wi, 256..511 Wr)
//   +2048   : scales f32[2] (si, sr) written by quant_k
//   +4096   : Qi  bf16 ints, 2 MB
//   +2M+4096: Qr  bf16 ints, 2 MB
//   +4M+4096: Abf bf16, 8 MB
//   +12M+..: Hbf bf16, 8 MB
//   +20M+..: Xq  bf16 (x pre-LN, unscaled), 8 MB
//   +28M+..: Hq  bf16 (h pre-LN, unscaled), 8 MB

typedef float  f32x4  __attribute__((ext_vector_type(4)));
typedef __bf16 bf16x8 __attribute__((ext_vector_type(8)));
typedef __bf16 bf16x4 __attribute__((ext_vector_type(4)));

#define KDIM 1024

// ---------------- fused: weight absmax (blocks 0..511) + activation cvt (512..2559) ----------------
__global__ __launch_bounds__(256)
void prep1_k(const float* __restrict__ A, const float* __restrict__ Hh,
             const float* __restrict__ Wi, const float* __restrict__ Wr,
             float* __restrict__ bmax,
             __bf16* __restrict__ Abf, __bf16* __restrict__ Hbf)
{
    const int b = blockIdx.x, t = threadIdx.x;
    if (b < 512) {
        const int tensor = b >> 8;
        const float* W = tensor ? Wr : Wi;
        const int lane = t & 63, wid = t >> 6;
        const f32x4* p = (const f32x4*)W;
        const size_t base = (size_t)(b & 255) * 1024;
        float m = 0.f;
#pragma unroll
        for (int k = 0; k < 4; ++k) {
            f32x4 v = p[base + k * 256 + t];
            m = fmaxf(m, fmaxf(fmaxf(fabsf(v[0]), fabsf(v[1])),
                               fmaxf(fabsf(v[2]), fabsf(v[3]))));
        }
#pragma unroll
        for (int o = 32; o >= 1; o >>= 1) m = fmaxf(m, __shfl_xor(m, o));
        __shared__ float wm_[4];
        if (lane == 0) wm_[wid] = m;
        __syncthreads();
        if (t == 0) bmax[b] = fmaxf(fmaxf(wm_[0], wm_[1]), fmaxf(wm_[2], wm_[3]));
        return;
    }
    // activation f32 -> bf16
    const int c = b - 512;                       // 0..2047
    const float* src = (c < 1024) ? A : Hh;
    __bf16* dst = (c < 1024) ? Abf : Hbf;
    const int base = (c & 1023) * 4096;
#pragma unroll
    for (int j = 0; j < 2; ++j) {
        const int e = base + (j * 256 + t) * 8;
        f32x4 v0 = ((const f32x4*)(src + e))[0];
        f32x4 v1 = ((const f32x4*)(src + e))[1];
        bf16x8 o;
#pragma unroll
        for (int i = 0; i < 4; ++i) {
            o[i]     = (__bf16)v0[i];
            o[i + 4] = (__bf16)v1[i];
        }
        *(bf16x8*)(dst + e) = o;
    }
}

// ---------------- quantize weights to integer bf16 (reduces bmax per block) ----------------
__global__ __launch_bounds__(256)
void quant_k(const float* __restrict__ Wi, const float* __restrict__ Wr,
             const float* __restrict__ bmax, float* __restrict__ scales,
             __bf16* __restrict__ Qi, __bf16* __restrict__ Qr)
{
    const int tensor = blockIdx.x >> 8;
    const int b = blockIdx.x & 255;
    const int t = threadIdx.x;
    const int lane = t & 63, wid = t >> 6;

    // reduce the 256 per-block maxes of this tensor
    float m = bmax[tensor * 256 + t];
#pragma unroll
    for (int o = 32; o >= 1; o >>= 1) m = fmaxf(m, __shfl_xor(m, o));
    __shared__ float wm_[4];
    if (lane == 0) wm_[wid] = m;
    __syncthreads();
    m = fmaxf(fmaxf(wm_[0], wm_[1]), fmaxf(wm_[2], wm_[3]));
    const float s = m / 7.0f;
    if (t == 0 && b == 0) scales[tensor] = s;    // publish for ln_tanh

    const float* W = tensor ? Wr : Wi;
    __bf16* Q = tensor ? Qr : Qi;
#pragma unroll
    for (int j = 0; j < 2; ++j) {
        const int e = b * 4096 + (j * 256 + t) * 8;
        f32x4 v0 = ((const f32x4*)(W + e))[0];
        f32x4 v1 = ((const f32x4*)(W + e))[1];
        bf16x8 o;
#pragma unroll
        for (int i = 0; i < 4; ++i) {
            o[i]     = (__bf16)rintf(v0[i] / s);
            o[i + 4] = (__bf16)rintf(v1[i] / s);
        }
        *(bf16x8*)(Q + e) = o;
    }
}

// ---------------- dual bf16 MFMA GEMM: 256x128 tile, 8-wave, counted-vmcnt pipeline ----------------
// BK=64, 16 K-steps, 3 LDS buffers (distance-2 prefetch), 2 phases/K-step.
// LDS chunk layout linear for global_load_lds; XOR swizzle applied on the
// per-lane GLOBAL source address; ds_read applies the same involution.
// Per phase: {8 ds_read_b128 | 3 global_load_lds -> barrier -> lgkmcnt(0) ->
//             setprio(1) 16 MFMA setprio(0) -> barrier}; vmcnt(6) once per
// K-step (never 0 in the main loop).
__global__ __launch_bounds__(512, 2)
void gemm_dual(const __bf16* __restrict__ A0, const __bf16* __restrict__ A1,
               const __bf16* __restrict__ W0, const __bf16* __restrict__ W1,
               __bf16* __restrict__ C0, __bf16* __restrict__ C1)
{
    __shared__ bf16x8 lds[3][3072];   // [buf][A:0..2047 | B:2048..3071] = 144 KB

    // XCD-aware bijective swizzle (256 blocks, 8 XCDs)
    const int b = blockIdx.x;
    const int swz = (b & 7) * 32 + (b >> 3);
    const int which = swz >> 7;
    const int r = swz & 127;
    const int bm = r >> 3, bn = r & 7;     // bm 0..15 (M/256), bn 0..7 (N/128)

    const __bf16* A = which ? A1 : A0;
    const __bf16* W = which ? W1 : W0;
    __bf16*       C = which ? C1 : C0;

    const int t = threadIdx.x;
    const int l = t & 63, w = t >> 6;
    const int wm = w >> 1, wn = w & 1;      // wave grid 4M x 2N, per-wave 64x64
    const int l15 = l & 15, l7 = l & 7, lq = l >> 4;

    const __bf16* gA = A + (size_t)(bm * 256) * KDIM;
    const __bf16* gB = W + (size_t)(bn * 128) * KDIM;

    // staging source offsets (element units), pre-swizzled
    int srcA[4], srcB[2];
#pragma unroll
    for (int j = 0; j < 4; ++j) {
        const int c = j * 512 + t;          // A chunk 0..2047
        const int row = c >> 3, g = (c & 7) ^ (row & 7);
        srcA[j] = row * KDIM + g * 8;
    }
#pragma unroll
    for (int j = 0; j < 2; ++j) {
        const int c = j * 512 + t;          // B chunk 0..1023
        const int row = c >> 3, g = (c & 7) ^ (row & 7);
        srcB[j] = row * KDIM + g * 8;
    }

#define GLLA(bb, j, kt)                                                        \
    __builtin_amdgcn_global_load_lds(                                          \
        (const __attribute__((address_space(1))) unsigned*)(gA + srcA[j] + (kt) * 64), \
        (__attribute__((address_space(3))) unsigned*)(&lds[bb][(j) * 512 + t]),\
        16, 0, 0)
#define GLLB(bb, j, kt)                                                        \
    __builtin_amdgcn_global_load_lds(                                          \
        (const __attribute__((address_space(1))) unsigned*)(gB + srcB[j] + (kt) * 64), \
        (__attribute__((address_space(3))) unsigned*)(&lds[bb][2048 + (j) * 512 + t]), \
        16, 0, 0)

    const f32x4 zero4 = {0.f, 0.f, 0.f, 0.f};
    f32x4 acc[4][4];
#pragma unroll
    for (int mi = 0; mi < 4; ++mi)
#pragma unroll
        for (int ni = 0; ni < 4; ++ni) acc[mi][ni] = zero4;

    // prologue: stage kt=0 -> buf0, kt=1 -> buf1 (12 loads in flight)
    GLLA(0, 0, 0); GLLA(0, 1, 0); GLLA(0, 2, 0); GLLA(0, 3, 0);
    GLLB(0, 0, 0); GLLB(0, 1, 0);
    GLLA(1, 0, 1); GLLA(1, 1, 1); GLLA(1, 2, 1); GLLA(1, 3, 1);
    GLLB(1, 0, 1); GLLB(1, 1, 1);
    asm volatile("s_waitcnt vmcnt(6)" ::: "memory");   // buf0 landed, buf1 in flight
    __builtin_amdgcn_s_barrier();

    int cur = 0, nx2 = 2;
    for (int kt = 0; kt < 16; ++kt) {
        const bf16x8* LA = &lds[cur][0];
        const bf16x8* LB = &lds[cur][2048];
        bf16x8 af[4], bfv[4];

        // ---------- phase 0 (kk = 0) ----------
        {
            const int kq = lq;
#pragma unroll
            for (int mi = 0; mi < 4; ++mi)
                af[mi] = LA[(wm * 64 + mi * 16 + l15) * 8 + (kq ^ l7)];
#pragma unroll
            for (int ni = 0; ni < 4; ++ni)
                bfv[ni] = LB[(wn * 64 + ni * 16 + l15) * 8 + (kq ^ l7)];
        }
        if (kt < 14) { GLLA(nx2, 0, kt + 2); GLLA(nx2, 1, kt + 2); GLLA(nx2, 2, kt + 2); }
        __builtin_amdgcn_s_barrier();
        asm volatile("s_waitcnt lgkmcnt(0)" ::: "memory");
        __builtin_amdgcn_sched_barrier(0);
        __builtin_amdgcn_s_setprio(1);
#pragma unroll
        for (int mi = 0; mi < 4; ++mi)
#pragma unroll
            for (int ni = 0; ni < 4; ++ni)
                acc[mi][ni] = __builtin_amdgcn_mfma_f32_16x16x32_bf16(
                    bfv[ni], af[mi], acc[mi][ni], 0, 0, 0);
        __builtin_amdgcn_s_setprio(0);
        __builtin_amdgcn_s_barrier();

        // ---------- phase 1 (kk = 1) ----------
        {
            const int kq = 4 + lq;
#pragma unroll
            for (int mi = 0; mi < 4; ++mi)
                af[mi] = LA[(wm * 64 + mi * 16 + l15) * 8 + (kq ^ l7)];
#pragma unroll
            for (int ni = 0; ni < 4; ++ni)
                bfv[ni] = LB[(wn * 64 + ni * 16 + l15) * 8 + (kq ^ l7)];
        }
        if (kt < 14) { GLLA(nx2, 3, kt + 2); GLLB(nx2, 0, kt + 2); GLLB(nx2, 1, kt + 2); }
        if (kt < 14)       { asm volatile("s_waitcnt vmcnt(6)" ::: "memory"); }
        else if (kt == 14) { asm volatile("s_waitcnt vmcnt(0)" ::: "memory"); }
        __builtin_amdgcn_s_barrier();
        asm volatile("s_waitcnt lgkmcnt(0)" ::: "memory");
        __builtin_amdgcn_sched_barrier(0);
        __builtin_amdgcn_s_setprio(1);
#pragma unroll
        for (int mi = 0; mi < 4; ++mi)
#pragma unroll
            for (int ni = 0; ni < 4; ++ni)
                acc[mi][ni] = __builtin_amdgcn_mfma_f32_16x16x32_bf16(
                    bfv[ni], af[mi], acc[mi][ni], 0, 0, 0);
        __builtin_amdgcn_s_setprio(0);
        __builtin_amdgcn_s_barrier();

        cur = (cur == 2) ? 0 : cur + 1;
        nx2 = (nx2 == 2) ? 0 : nx2 + 1;
    }

    // C write (swapped-operand layout): batch = lane&15 (+mi*16),
    // feat = (lane>>4)*4 + rr (+ni*16); one 8B bf16x4 store per fragment
    const int batch0 = bm * 256 + wm * 64 + l15;
    const int feat0  = bn * 128 + wn * 64 + (lq << 2);
#pragma unroll
    for (int mi = 0; mi < 4; ++mi)
#pragma unroll
        for (int ni = 0; ni < 4; ++ni) {
            bf16x4 o;
#pragma unroll
            for (int rr = 0; rr < 4; ++rr) o[rr] = (__bf16)acc[mi][ni][rr];
            *(bf16x4*)(C + (size_t)(batch0 + mi * 16) * KDIM + feat0 + ni * 16) = o;
        }
#undef GLLA
#undef GLLB
}

// ---------------- fused scale+bias, LN(x), LN(h), tanh ----------------
__global__ __launch_bounds__(256)
void ln_tanh_k(const __bf16* __restrict__ X, const __bf16* __restrict__ Hh,
               const float* __restrict__ bi, const float* __restrict__ br,
               const float* __restrict__ scales, float* __restrict__ out)
{
    const int row = blockIdx.x;
    const int t = threadIdx.x;
    const int lane = t & 63, wid = t >> 6;
    const float si = scales[0];
    const float sr = scales[1];

    bf16x4 xv = ((const bf16x4*)(X  + (size_t)row * 1024))[t];
    bf16x4 hv = ((const bf16x4*)(Hh + (size_t)row * 1024))[t];
    f32x4 bvi = ((const f32x4*)bi)[t];
    f32x4 bvr = ((const f32x4*)br)[t];

    float xs[4], hs[4];
    float sx = 0.f, sh = 0.f;
#pragma unroll
    for (int j = 0; j < 4; ++j) {
        xs[j] = (float)xv[j] * si + bvi[j];
        hs[j] = (float)hv[j] * sr + bvr[j];
        sx += xs[j]; sh += hs[j];
    }

    __shared__ float rb[2][4];
#pragma unroll
    for (int o = 32; o >= 1; o >>= 1) { sx += __shfl_xor(sx, o); sh += __shfl_xor(sh, o); }
    if (lane == 0) { rb[0][wid] = sx; rb[1][wid] = sh; }
    __syncthreads();
    sx = rb[0][0] + rb[0][1] + rb[0][2] + rb[0][3];
    sh = rb[1][0] + rb[1][1] + rb[1][2] + rb[1][3];
    const float mx = sx * (1.0f / 1024.0f), mh = sh * (1.0f / 1024.0f);

    float vx = 0.f, vh = 0.f;
#pragma unroll
    for (int j = 0; j < 4; ++j) {
        xs[j] -= mx; hs[j] -= mh;
        vx += xs[j] * xs[j]; vh += hs[j] * hs[j];
    }
    __syncthreads();   // rb reuse
#pragma unroll
    for (int o = 32; o >= 1; o >>= 1) { vx += __shfl_xor(vx, o); vh += __shfl_xor(vh, o); }
    if (lane == 0) { rb[0][wid] = vx; rb[1][wid] = vh; }
    __syncthreads();
    vx = rb[0][0] + rb[0][1] + rb[0][2] + rb[0][3];
    vh = rb[1][0] + rb[1][1] + rb[1][2] + rb[1][3];
    const float rsx = rsqrtf(vx * (1.0f / 1024.0f) + 1e-5f);
    const float rsh = rsqrtf(vh * (1.0f / 1024.0f) + 1e-5f);

    f32x4 o4;
#pragma unroll
    for (int j = 0; j < 4; ++j) o4[j] = tanhf(xs[j] * rsx + hs[j] * rsh);
    ((f32x4*)(out + (size_t)row * 1024))[t] = o4;
}

extern "C" void kernel_launch(void* const* d_in, const int* in_sizes, int n_in,
                              void* d_out, int out_size, void* d_ws, size_t ws_size,
                              hipStream_t stream)
{
    const float* input_ = (const float*)d_in[0];
    const float* hidden = (const float*)d_in[1];
    const float* Wi     = (const float*)d_in[2];
    const float* bi     = (const float*)d_in[3];
    const float* Wr     = (const float*)d_in[4];
    const float* br     = (const float*)d_in[5];
    float* out = (float*)d_out;

    char* ws = (char*)d_ws;
    float* bmax   = (float*)ws;
    float* scales = (float*)(ws + 2048);
    __bf16* Qi  = (__bf16*)(ws + 4096);
    __bf16* Qr  = (__bf16*)(ws + 4096 + (1u << 21));
    __bf16* Abf = (__bf16*)(ws + 4096 + (2u << 21));
    __bf16* Hbf = (__bf16*)(ws + 4096 + (2u << 21) + (1u << 23));
    __bf16* Xq  = (__bf16*)(ws + 4096 + (2u << 21) + (2u << 23));
    __bf16* Hq  = (__bf16*)(ws + 4096 + (2u << 21) + (3u << 23));

    prep1_k<<<2560, 256, 0, stream>>>(input_, hidden, Wi, Wr, bmax, Abf, Hbf);
    quant_k<<<512, 256, 0, stream>>>(Wi, Wr, bmax, scales, Qi, Qr);
    gemm_dual<<<256, 512, 0, stream>>>(Abf, Hbf, Qi, Qr, Xq, Hq);
    ln_tanh_k<<<4096, 256, 0, stream>>>(Xq, Hq, bi, br, scales, out);
}

// Round 5
// 49.136 us; speedup vs baseline: 1.2121x; 1.0093x over previous
//
#include <hip/hip_runtime.h>
#include <hip/hip_bf16.h>

// Problem: B=4096, D_IN=D_H=K=1024.
//   x = input_ @ fq(Wi,4).T + bi ; h = hidden @ fq(Wr,4).T + br
//   out = tanh(LN(x) + LN(h))
// ws layout:
//   +0      : bmax f32[512] (per-block weight absmax; 0..255 Wi, 256..511 Wr)
//   +2048   : scales f32[2] (si, sr) written by quant_k
//   +4096   : Qi  bf16 ints, 2 MB
//   +2M+4096: Qr  bf16 ints, 2 MB
//   +4M+4096: Abf bf16, 8 MB
//   +12M+..: Hbf bf16, 8 MB
//   +20M+..: Xq  bf16 (x pre-LN, unscaled), 8 MB
//   +28M+..: Hq  bf16 (h pre-LN, unscaled), 8 MB

typedef float  f32x4  __attribute__((ext_vector_type(4)));
typedef __bf16 bf16x8 __attribute__((ext_vector_type(8)));
typedef __bf16 bf16x4 __attribute__((ext_vector_type(4)));

#define KDIM 1024

// ---------------- fused: weight absmax (blocks 0..511) + activation cvt (512..2559) ----------------
__global__ __launch_bounds__(256)
void prep1_k(const float* __restrict__ A, const float* __restrict__ Hh,
             const float* __restrict__ Wi, const float* __restrict__ Wr,
             float* __restrict__ bmax,
             __bf16* __restrict__ Abf, __bf16* __restrict__ Hbf)
{
    const int b = blockIdx.x, t = threadIdx.x;
    if (b < 512) {
        const int tensor = b >> 8;
        const float* W = tensor ? Wr : Wi;
        const int lane = t & 63, wid = t >> 6;
        const f32x4* p = (const f32x4*)W;
        const size_t base = (size_t)(b & 255) * 1024;
        float m = 0.f;
#pragma unroll
        for (int k = 0; k < 4; ++k) {
            f32x4 v = p[base + k * 256 + t];
            m = fmaxf(m, fmaxf(fmaxf(fabsf(v[0]), fabsf(v[1])),
                               fmaxf(fabsf(v[2]), fabsf(v[3]))));
        }
#pragma unroll
        for (int o = 32; o >= 1; o >>= 1) m = fmaxf(m, __shfl_xor(m, o));
        __shared__ float wm_[4];
        if (lane == 0) wm_[wid] = m;
        __syncthreads();
        if (t == 0) bmax[b] = fmaxf(fmaxf(wm_[0], wm_[1]), fmaxf(wm_[2], wm_[3]));
        return;
    }
    // activation f32 -> bf16
    const int c = b - 512;                       // 0..2047
    const float* src = (c < 1024) ? A : Hh;
    __bf16* dst = (c < 1024) ? Abf : Hbf;
    const int base = (c & 1023) * 4096;
#pragma unroll
    for (int j = 0; j < 2; ++j) {
        const int e = base + (j * 256 + t) * 8;
        f32x4 v0 = ((const f32x4*)(src + e))[0];
        f32x4 v1 = ((const f32x4*)(src + e))[1];
        bf16x8 o;
#pragma unroll
        for (int i = 0; i < 4; ++i) {
            o[i]     = (__bf16)v0[i];
            o[i + 4] = (__bf16)v1[i];
        }
        *(bf16x8*)(dst + e) = o;
    }
}

// ---------------- quantize weights to integer bf16 (reduces bmax per block) ----------------
__global__ __launch_bounds__(256)
void quant_k(const float* __restrict__ Wi, const float* __restrict__ Wr,
             const float* __restrict__ bmax, float* __restrict__ scales,
             __bf16* __restrict__ Qi, __bf16* __restrict__ Qr)
{
    const int tensor = blockIdx.x >> 8;
    const int b = blockIdx.x & 255;
    const int t = threadIdx.x;
    const int lane = t & 63, wid = t >> 6;

    float m = bmax[tensor * 256 + t];
#pragma unroll
    for (int o = 32; o >= 1; o >>= 1) m = fmaxf(m, __shfl_xor(m, o));
    __shared__ float wm_[4];
    if (lane == 0) wm_[wid] = m;
    __syncthreads();
    m = fmaxf(fmaxf(wm_[0], wm_[1]), fmaxf(wm_[2], wm_[3]));
    const float s = m / 7.0f;
    if (t == 0 && b == 0) scales[tensor] = s;

    const float* W = tensor ? Wr : Wi;
    __bf16* Q = tensor ? Qr : Qi;
#pragma unroll
    for (int j = 0; j < 2; ++j) {
        const int e = b * 4096 + (j * 256 + t) * 8;
        f32x4 v0 = ((const f32x4*)(W + e))[0];
        f32x4 v1 = ((const f32x4*)(W + e))[1];
        bf16x8 o;
#pragma unroll
        for (int i = 0; i < 4; ++i) {
            o[i]     = (__bf16)rintf(v0[i] / s);
            o[i + 4] = (__bf16)rintf(v1[i] / s);
        }
        *(bf16x8*)(Q + e) = o;
    }
}

// ---------------- dual bf16 MFMA GEMM: 256x128 tile, 8-wave, single-barrier pipeline ----------------
// BK=64, 16 K-steps, 3 LDS buffers (distance-2 prefetch), ONE barrier per K-step.
// Iteration: [16 ds_read | stage 6 gloads(kt+2) | lgkmcnt(0) | 32 MFMA |
//             vmcnt(6) | s_barrier]. Race-freedom:
//  (a) buf[kt+1] reads: each wave's vmcnt(6)@kt retires stage(kt+1) (in-order
//      vmcnt), then the collective barrier -> reads at kt+1 safe.
//  (b) stage(kt+2) overwrites buf[(kt-1)%3]: every wave ran lgkmcnt(0)@kt-1
//      (retiring its reads of that buf) BEFORE barrier(kt-1); stage is after.
// Raw s_barrier (not __syncthreads) so no vmcnt(0) drain is injected.
__global__ __launch_bounds__(512, 2)
void gemm_dual(const __bf16* __restrict__ A0, const __bf16* __restrict__ A1,
               const __bf16* __restrict__ W0, const __bf16* __restrict__ W1,
               __bf16* __restrict__ C0, __bf16* __restrict__ C1)
{
    __shared__ bf16x8 lds[3][3072];   // [buf][A:0..2047 | B:2048..3071] = 144 KB

    // XCD-aware bijective swizzle (256 blocks, 8 XCDs)
    const int b = blockIdx.x;
    const int swz = (b & 7) * 32 + (b >> 3);
    const int which = swz >> 7;
    const int r = swz & 127;
    const int bm = r >> 3, bn = r & 7;     // bm 0..15 (M/256), bn 0..7 (N/128)

    const __bf16* A = which ? A1 : A0;
    const __bf16* W = which ? W1 : W0;
    __bf16*       C = which ? C1 : C0;

    const int t = threadIdx.x;
    const int l = t & 63, w = t >> 6;
    const int wm = w >> 1, wn = w & 1;      // wave grid 4M x 2N, per-wave 64x64
    const int l15 = l & 15, l7 = l & 7, lq = l >> 4;

    const __bf16* gA = A + (size_t)(bm * 256) * KDIM;
    const __bf16* gB = W + (size_t)(bn * 128) * KDIM;

    // staging source offsets (element units), pre-swizzled
    int srcA[4], srcB[2];
#pragma unroll
    for (int j = 0; j < 4; ++j) {
        const int c = j * 512 + t;          // A chunk 0..2047
        const int row = c >> 3, g = (c & 7) ^ (row & 7);
        srcA[j] = row * KDIM + g * 8;
    }
#pragma unroll
    for (int j = 0; j < 2; ++j) {
        const int c = j * 512 + t;          // B chunk 0..1023
        const int row = c >> 3, g = (c & 7) ^ (row & 7);
        srcB[j] = row * KDIM + g * 8;
    }

#define STAGE(bb, kt)                                                          \
    do {                                                                       \
        _Pragma("unroll")                                                      \
        for (int j = 0; j < 4; ++j)                                            \
            __builtin_amdgcn_global_load_lds(                                  \
                (const __attribute__((address_space(1))) unsigned*)(gA + srcA[j] + (kt) * 64), \
                (__attribute__((address_space(3))) unsigned*)(&lds[bb][(j) * 512 + t]), \
                16, 0, 0);                                                     \
        _Pragma("unroll")                                                      \
        for (int j = 0; j < 2; ++j)                                            \
            __builtin_amdgcn_global_load_lds(                                  \
                (const __attribute__((address_space(1))) unsigned*)(gB + srcB[j] + (kt) * 64), \
                (__attribute__((address_space(3))) unsigned*)(&lds[bb][2048 + (j) * 512 + t]), \
                16, 0, 0);                                                     \
    } while (0)

    const f32x4 zero4 = {0.f, 0.f, 0.f, 0.f};
    f32x4 acc[4][4];
#pragma unroll
    for (int mi = 0; mi < 4; ++mi)
#pragma unroll
        for (int ni = 0; ni < 4; ++ni) acc[mi][ni] = zero4;

    // prologue: stage kt=0 -> buf0, kt=1 -> buf1 (12 loads in flight)
    STAGE(0, 0);
    STAGE(1, 1);
    asm volatile("s_waitcnt vmcnt(6)" ::: "memory");   // buf0 landed
    __builtin_amdgcn_s_barrier();

    int cur = 0, nx2 = 2;
    for (int kt = 0; kt < 16; ++kt) {
        const bf16x8* LA = &lds[cur][0];
        const bf16x8* LB = &lds[cur][2048];
        bf16x8 af[2][4], bfv[2][4];

        // 16 ds_read_b128 (both kk halves)
#pragma unroll
        for (int kk = 0; kk < 2; ++kk) {
            const int kq = kk * 4 + lq;
#pragma unroll
            for (int mi = 0; mi < 4; ++mi)
                af[kk][mi] = LA[(wm * 64 + mi * 16 + l15) * 8 + (kq ^ l7)];
#pragma unroll
            for (int ni = 0; ni < 4; ++ni)
                bfv[kk][ni] = LB[(wn * 64 + ni * 16 + l15) * 8 + (kq ^ l7)];
        }

        // prefetch kt+2 (6 loads) while reads are in flight
        if (kt < 14) STAGE(nx2, kt + 2);

        asm volatile("s_waitcnt lgkmcnt(0)" ::: "memory");   // reads retired (b)
        __builtin_amdgcn_sched_barrier(0);

        __builtin_amdgcn_s_setprio(1);
#pragma unroll
        for (int kk = 0; kk < 2; ++kk)
#pragma unroll
            for (int mi = 0; mi < 4; ++mi)
#pragma unroll
                for (int ni = 0; ni < 4; ++ni)
                    acc[mi][ni] = __builtin_amdgcn_mfma_f32_16x16x32_bf16(
                        bfv[kk][ni], af[kk][mi], acc[mi][ni], 0, 0, 0);
        __builtin_amdgcn_s_setprio(0);

        if (kt < 14)       { asm volatile("s_waitcnt vmcnt(6)" ::: "memory"); }  // certify kt+1
        else if (kt == 14) { asm volatile("s_waitcnt vmcnt(0)" ::: "memory"); }  // tail: certify 15
        if (kt < 15) __builtin_amdgcn_s_barrier();

        cur = (cur == 2) ? 0 : cur + 1;
        nx2 = (nx2 == 2) ? 0 : nx2 + 1;
    }

    // C write (swapped-operand layout): batch = lane&15 (+mi*16),
    // feat = (lane>>4)*4 + rr (+ni*16); one 8B bf16x4 store per fragment
    const int batch0 = bm * 256 + wm * 64 + l15;
    const int feat0  = bn * 128 + wn * 64 + (lq << 2);
#pragma unroll
    for (int mi = 0; mi < 4; ++mi)
#pragma unroll
        for (int ni = 0; ni < 4; ++ni) {
            bf16x4 o;
#pragma unroll
            for (int rr = 0; rr < 4; ++rr) o[rr] = (__bf16)acc[mi][ni][rr];
            *(bf16x4*)(C + (size_t)(batch0 + mi * 16) * KDIM + feat0 + ni * 16) = o;
        }
#undef STAGE
}

// ---------------- fused scale+bias, LN(x), LN(h), tanh — one row per WAVE ----------------
__global__ __launch_bounds__(256)
void ln_tanh_k(const __bf16* __restrict__ X, const __bf16* __restrict__ Hh,
               const float* __restrict__ bi, const float* __restrict__ br,
               const float* __restrict__ scales, float* __restrict__ out)
{
    const int t = threadIdx.x;
    const int lane = t & 63, wid = t >> 6;
    const int row = blockIdx.x * 4 + wid;
    const float si = scales[0];
    const float sr = scales[1];

    const bf16x8* xp = (const bf16x8*)(X  + (size_t)row * 1024 + lane * 16);
    const bf16x8* hp = (const bf16x8*)(Hh + (size_t)row * 1024 + lane * 16);
    bf16x8 xv0 = xp[0], xv1 = xp[1];
    bf16x8 hv0 = hp[0], hv1 = hp[1];

    float xs[16], hs[16];
    float sx = 0.f, sh = 0.f;
#pragma unroll
    for (int q = 0; q < 4; ++q) {
        f32x4 bviq = ((const f32x4*)bi)[lane * 4 + q];
        f32x4 bvrq = ((const f32x4*)br)[lane * 4 + q];
#pragma unroll
        for (int j = 0; j < 4; ++j) {
            const int e = q * 4 + j;
            const float xf = (e < 8) ? (float)xv0[e] : (float)xv1[e - 8];
            const float hf = (e < 8) ? (float)hv0[e] : (float)hv1[e - 8];
            xs[e] = xf * si + bviq[j];
            hs[e] = hf * sr + bvrq[j];
            sx += xs[e]; sh += hs[e];
        }
    }

#pragma unroll
    for (int o = 32; o >= 1; o >>= 1) { sx += __shfl_xor(sx, o); sh += __shfl_xor(sh, o); }
    const float mx = sx * (1.0f / 1024.0f), mh = sh * (1.0f / 1024.0f);

    float vx = 0.f, vh = 0.f;
#pragma unroll
    for (int e = 0; e < 16; ++e) {
        xs[e] -= mx; hs[e] -= mh;
        vx += xs[e] * xs[e]; vh += hs[e] * hs[e];
    }
#pragma unroll
    for (int o = 32; o >= 1; o >>= 1) { vx += __shfl_xor(vx, o); vh += __shfl_xor(vh, o); }
    const float rsx = rsqrtf(vx * (1.0f / 1024.0f) + 1e-5f);
    const float rsh = rsqrtf(vh * (1.0f / 1024.0f) + 1e-5f);

    float* op = out + (size_t)row * 1024 + lane * 16;
#pragma unroll
    for (int q = 0; q < 4; ++q) {
        f32x4 o4;
#pragma unroll
        for (int j = 0; j < 4; ++j) {
            const int e = q * 4 + j;
            o4[j] = tanhf(xs[e] * rsx + hs[e] * rsh);
        }
        ((f32x4*)op)[q] = o4;
    }
}

extern "C" void kernel_launch(void* const* d_in, const int* in_sizes, int n_in,
                              void* d_out, int out_size, void* d_ws, size_t ws_size,
                              hipStream_t stream)
{
    const float* input_ = (const float*)d_in[0];
    const float* hidden = (const float*)d_in[1];
    const float* Wi     = (const float*)d_in[2];
    const float* bi     = (const float*)d_in[3];
    const float* Wr     = (const float*)d_in[4];
    const float* br     = (const float*)d_in[5];
    float* out = (float*)d_out;

    char* ws = (char*)d_ws;
    float* bmax   = (float*)ws;
    float* scales = (float*)(ws + 2048);
    __bf16* Qi  = (__bf16*)(ws + 4096);
    __bf16* Qr  = (__bf16*)(ws + 4096 + (1u << 21));
    __bf16* Abf = (__bf16*)(ws + 4096 + (2u << 21));
    __bf16* Hbf = (__bf16*)(ws + 4096 + (2u << 21) + (1u << 23));
    __bf16* Xq  = (__bf16*)(ws + 4096 + (2u << 21) + (2u << 23));
    __bf16* Hq  = (__bf16*)(ws + 4096 + (2u << 21) + (3u << 23));

    prep1_k<<<2560, 256, 0, stream>>>(input_, hidden, Wi, Wr, bmax, Abf, Hbf);
    quant_k<<<512, 256, 0, stream>>>(Wi, Wr, bmax, scales, Qi, Qr);
    gemm_dual<<<256, 512, 0, stream>>>(Abf, Hbf, Qi, Qr, Xq, Hq);
    ln_tanh_k<<<1024, 256, 0, stream>>>(Xq, Hq, bi, br, scales, out);
}